// Round 14
// baseline (628.200 us; speedup 1.0000x reference)
//
#include <hip/hip_runtime.h>
#include <stdint.h>

#define T 49
#define CCH 256

typedef __bf16 bf16x8 __attribute__((ext_vector_type(8)));
typedef float f32x4 __attribute__((ext_vector_type(4)));

static __device__ __forceinline__ unsigned short f2bf(float f){
  __bf16 h = (__bf16)f;
  return __builtin_bit_cast(unsigned short, h);
}
static __device__ __forceinline__ uint32_t pk2(float a, float b){
  return (uint32_t)f2bf(a) | ((uint32_t)f2bf(b) << 16);
}
static __device__ __forceinline__ f32x4 mfma16(bf16x8 a, bf16x8 b, f32x4 c){
  return __builtin_amdgcn_mfma_f32_16x16x32_bf16(a, b, c, 0, 0, 0);
}
static __device__ __forceinline__ float max3f(float a, float b, float c){
  return fmaxf(fmaxf(a, b), c);   // fuses to v_max3_f32
}
#define SWZ(row) ((((row) & 7) << 4))

static __device__ __forceinline__ bf16x8 build_frag(uint32_t lo_w0, uint32_t lo_w1,
                                                    uint32_t hi_w0, uint32_t hi_w1,
                                                    int srcA, int srcB, bool use_hi){
  uint32_t a0 = (uint32_t)__shfl((int)lo_w0, srcA, 64);
  uint32_t c0 = (uint32_t)__shfl((int)hi_w0, srcA, 64);
  uint32_t a1 = (uint32_t)__shfl((int)lo_w1, srcA, 64);
  uint32_t c1 = (uint32_t)__shfl((int)hi_w1, srcA, 64);
  uint32_t a2 = (uint32_t)__shfl((int)lo_w0, srcB, 64);
  uint32_t c2 = (uint32_t)__shfl((int)hi_w0, srcB, 64);
  uint32_t a3 = (uint32_t)__shfl((int)lo_w1, srcB, 64);
  uint32_t c3 = (uint32_t)__shfl((int)hi_w1, srcB, 64);
  uint4 u = use_hi ? make_uint4(c0, c1, c2, c3) : make_uint4(a0, a1, a2, a3);
  return __builtin_bit_cast(bf16x8, u);
}

// ---------------- prep kernels (validated) ----------------

__global__ void prep_wqkvT(const float* __restrict__ wq, const float* __restrict__ wk,
                           const float* __restrict__ wv, unsigned short* __restrict__ out){
  int bk = blockIdx.x;            // 0..767
  int p = bk >> 8, kk = bk & 255;
  int n = threadIdx.x;
  const float* w = (p == 0) ? wq : (p == 1 ? wk : wv);
  float scl = (p == 0) ? 0.17677669529663687f : 1.0f;
  out[(size_t)(p * 256 + n) * 256 + kk] = f2bf(w[kk * 256 + n] * scl);
}

__global__ void prep_wodT(const float* __restrict__ wo, const float* __restrict__ dw,
                          unsigned short* __restrict__ out){
  int hd = blockIdx.x;            // 0..255
  int c = threadIdx.x;            // 0..255
  float s = 0.f;
  for (int cp = 0; cp < 256; ++cp) s = fmaf(wo[hd * 256 + cp], dw[cp * 256 + c], s);
  out[(size_t)c * 256 + hd] = f2bf(s);
}

// block 0: bqkv (q-scaled) + bod
// blocks 1..8: biasF (FLOAT) [h][jt][nt][g*16+lo][r] = bias(j=16jt+4g+r, i=16nt+lo)
__global__ void prep_misc(const int* __restrict__ rp, const float* __restrict__ btab,
                          const float* __restrict__ bq, const float* __restrict__ bk,
                          const float* __restrict__ bv, const float* __restrict__ bo,
                          const float* __restrict__ dwm, const float* __restrict__ db,
                          float* __restrict__ biasF, float* __restrict__ bqkv,
                          float* __restrict__ bod){
  int t = threadIdx.x;
  if (blockIdx.x == 0){
    for (int idx = t; idx < 768; idx += 256){
      int p = idx >> 8, n = idx & 255;
      float v = (p == 0) ? bq[n] * 0.17677669529663687f : (p == 1 ? bk[n] : bv[n]);
      bqkv[idx] = v;
    }
    float s = db[t];
    for (int cp = 0; cp < 256; ++cp) s = fmaf(bo[cp], dwm[cp * 256 + t], s);
    bod[t] = s;
  } else {
    int h = blockIdx.x - 1;
    for (int idx = t; idx < 4096; idx += 256){
      int r  = idx & 3;
      int lo = (idx >> 2) & 15;
      int g  = (idx >> 6) & 3;
      int nt = (idx >> 8) & 3;
      int jt = idx >> 10;
      int j = 16 * jt + 4 * g + r;
      int i = 16 * nt + lo;
      float v;
      if (j >= T) v = -1e30f;
      else if (i >= T) v = 0.f;
      else {
        int r0 = rp[i * 49 + j];
        int r1 = rp[2401 + i * 49 + j];
        v = btab[h * 169 + r0 * 13 + r1];
      }
      biasF[h * 4096 + idx] = v;   // idx = jt*1024 + nt*256 + g*64 + lo*4 + r
    }
  }
}

// ---------------- fused main kernel: (512,2) deep-ILP variant ----------------
// 1 block/CU, 8 waves, 256-reg budget. Merged K+Q pass with BOTH weight sets
// hoisted pre-barrier (inner loop = pure ds_read + 16 MFMA, dual 32-AGPR acc).
// V pass rolling-prefetched, av in-register. Final-GEMM weights hoisted right
// after the post-V barrier (latency hides under attention). biasF f32 + max3.
__launch_bounds__(512, 2)
__global__ void wmsa_main(const float* __restrict__ x,
                          const unsigned short* __restrict__ wqkvT,
                          const unsigned short* __restrict__ wodT,
                          const float* __restrict__ biasF,
                          const float* __restrict__ bqkv,
                          const float* __restrict__ bod,
                          float* __restrict__ y){
  __shared__ unsigned short xs[64 * 256];      // 32 KB, chunk^(row&7) swizzle

  const int b    = blockIdx.x;
  const int tid  = threadIdx.x;
  const int h    = tid >> 6;       // wave == head
  const int lane = tid & 63;
  const int g    = lane >> 4;
  const int lo   = lane & 15;
  char* xs_c = (char*)xs;

  // ---- per-lane constants & base registers ----
  const int  swz  = (lo & 7) << 4;
  const int  gq   = g >> 1;
  const int  gh   = (g & 1) * 8;
  const int  srcA = lo + 16 * ((2 * g) & 3);
  const int  srcB = lo + 16 * ((2 * g + 1) & 3);
  const bool ghi  = (g >= 2);

  const char* xb0 = xs_c + lo * 512 + ((16 * g) ^ swz);
  const char* xb1 = xs_c + lo * 512 + ((64 + 16 * g) ^ swz);

  const char* wk0 = (const char*)wqkvT + (size_t)(256 + h * 32 + lo) * 512 + 16 * g;
  const char* wk1 = wk0 + 16 * 512;
  const char* wq0 = (const char*)wqkvT + (size_t)(h * 32 + lo) * 512 + 16 * g;
  const char* wq1 = wq0 + 16 * 512;
  const char* wv0 = (const char*)wqkvT + (size_t)(512 + h * 32 + lo) * 512 + 16 * g;
  const char* wv1 = wv0 + 16 * 512;
  const char* wo0 = (const char*)wodT + (size_t)(h * 32 + lo) * 512 + 16 * g;
  const char* wo1 = wo0 + 16 * 512;

  // ---- stage x loads + hoist K AND Q weights (256-reg budget makes this fit) ----
  const float* xbp = x + (size_t)b * T * CCH;
  float4 vv[8];
  #pragma unroll
  for (int k2 = 0; k2 < 8; ++k2){
    int idx = tid + k2 * 512;
    int row = idx >> 6, c4 = idx & 63;
    vv[k2] = make_float4(0.f, 0.f, 0.f, 0.f);
    if (row < T) vv[k2] = reinterpret_cast<const float4*>(xbp)[row * 64 + c4];
  }
  bf16x8 kw0[8], kw1[8], qw0[8], qw1[8];
  #pragma unroll
  for (int kt = 0; kt < 8; ++kt){
    kw0[kt] = *reinterpret_cast<const bf16x8*>(wk0 + kt * 64);
    kw1[kt] = *reinterpret_cast<const bf16x8*>(wk1 + kt * 64);
    qw0[kt] = *reinterpret_cast<const bf16x8*>(wq0 + kt * 64);
    qw1[kt] = *reinterpret_cast<const bf16x8*>(wq1 + kt * 64);
  }
  #pragma unroll
  for (int k2 = 0; k2 < 8; ++k2){
    int idx = tid + k2 * 512;
    int row = idx >> 6, c4 = idx & 63;
    *reinterpret_cast<uint2*>(xs_c + row * 512 + ((c4 * 8) ^ SWZ(row)))
        = make_uint2(pk2(vv[k2].x, vv[k2].y), pk2(vv[k2].z, vv[k2].w));
  }
  __syncthreads();

  bf16x8 fk[4], fq[4], av[2][2];

  // ---- merged K+Q pass (transposed GEMMs, shared bx reads, dual acc) ----
  {
    f32x4 ak_[2][4], aq_[2][4];
    #pragma unroll
    for (int mt = 0; mt < 2; ++mt)
      #pragma unroll
      for (int nt = 0; nt < 4; ++nt){ ak_[mt][nt] = f32x4{0,0,0,0}; aq_[mt][nt] = f32x4{0,0,0,0}; }

    #pragma unroll 1
    for (int kb = 0; kb < 2; ++kb){
      #pragma unroll
      for (int q = 0; q < 4; ++q){
        const int kt = kb * 4 + q;
        const char* xb = (kt & 1) ? xb1 : xb0;
        const int  im  = (kt >> 1) * 128;
        bf16x8 bx[4];
        #pragma unroll
        for (int nt = 0; nt < 4; ++nt)
          bx[nt] = *reinterpret_cast<const bf16x8*>(xb + nt * 8192 + im);
        #pragma unroll
        for (int nt = 0; nt < 4; ++nt){
          ak_[0][nt] = mfma16(kw0[kt], bx[nt], ak_[0][nt]);
          ak_[1][nt] = mfma16(kw1[kt], bx[nt], ak_[1][nt]);
          aq_[0][nt] = mfma16(qw0[kt], bx[nt], aq_[0][nt]);
          aq_[1][nt] = mfma16(qw1[kt], bx[nt], aq_[1][nt]);
        }
      }
    }
    uint32_t pkk[2][4][2], pq[2][4][2];
    #pragma unroll
    for (int mt = 0; mt < 2; ++mt){
      const float4 b4k = *reinterpret_cast<const float4*>(bqkv + 256 + h * 32 + 16 * mt + 4 * g);
      const float4 b4q = *reinterpret_cast<const float4*>(bqkv + h * 32 + 16 * mt + 4 * g);
      #pragma unroll
      for (int nt = 0; nt < 4; ++nt){
        f32x4 tk = ak_[mt][nt], tq = aq_[mt][nt];
        tk[0] += b4k.x; tk[1] += b4k.y; tk[2] += b4k.z; tk[3] += b4k.w;
        tq[0] += b4q.x; tq[1] += b4q.y; tq[2] += b4q.z; tq[3] += b4q.w;
        pkk[mt][nt][0] = pk2(tk[0], tk[1]); pkk[mt][nt][1] = pk2(tk[2], tk[3]);
        pq[mt][nt][0]  = pk2(tq[0], tq[1]); pq[mt][nt][1]  = pk2(tq[2], tq[3]);
      }
    }
    #pragma unroll
    for (int nt = 0; nt < 4; ++nt){
      fk[nt] = build_frag(pkk[0][nt][0], pkk[0][nt][1], pkk[1][nt][0], pkk[1][nt][1], srcA, srcB, ghi);
      fq[nt] = build_frag(pq[0][nt][0],  pq[0][nt][1],  pq[1][nt][0],  pq[1][nt][1],  srcA, srcB, ghi);
    }
  }

  // ---- pass V (normal GEMM), rolling 2-deep weight prefetch; av in-register ----
  {
    f32x4 acc[4][2];
    #pragma unroll
    for (int mt = 0; mt < 4; ++mt)
      #pragma unroll
      for (int nt = 0; nt < 2; ++nt) acc[mt][nt] = f32x4{0,0,0,0};

    bf16x8 wE0 = *reinterpret_cast<const bf16x8*>(wv0);
    bf16x8 wE1 = *reinterpret_cast<const bf16x8*>(wv1);
    bf16x8 wO0 = *reinterpret_cast<const bf16x8*>(wv0 + 64);
    bf16x8 wO1 = *reinterpret_cast<const bf16x8*>(wv1 + 64);

    #pragma unroll 1
    for (int kp = 0; kp < 4; ++kp){
      const int nb = (kp < 3) ? (kp * 128 + 128) : 0;
      bf16x8 nE0 = *reinterpret_cast<const bf16x8*>(wv0 + nb);
      bf16x8 nE1 = *reinterpret_cast<const bf16x8*>(wv1 + nb);
      bf16x8 nO0 = *reinterpret_cast<const bf16x8*>(wv0 + nb + 64);
      bf16x8 nO1 = *reinterpret_cast<const bf16x8*>(wv1 + nb + 64);
      const int im = kp * 128;
      bf16x8 ax[4];
      #pragma unroll
      for (int mt = 0; mt < 4; ++mt)
        ax[mt] = *reinterpret_cast<const bf16x8*>(xb0 + mt * 8192 + im);
      #pragma unroll
      for (int mt = 0; mt < 4; ++mt){
        acc[mt][0] = mfma16(ax[mt], wE0, acc[mt][0]);
        acc[mt][1] = mfma16(ax[mt], wE1, acc[mt][1]);
      }
      #pragma unroll
      for (int mt = 0; mt < 4; ++mt)
        ax[mt] = *reinterpret_cast<const bf16x8*>(xb1 + mt * 8192 + im);
      #pragma unroll
      for (int mt = 0; mt < 4; ++mt){
        acc[mt][0] = mfma16(ax[mt], wO0, acc[mt][0]);
        acc[mt][1] = mfma16(ax[mt], wO1, acc[mt][1]);
      }
      wE0 = nE0; wE1 = nE1; wO0 = nO0; wO1 = nO1;
    }
    uint32_t pv[4][2][2];
    #pragma unroll
    for (int nt = 0; nt < 2; ++nt){
      const float bvs = bqkv[512 + h * 32 + 16 * nt + lo];
      #pragma unroll
      for (int mt = 0; mt < 4; ++mt){
        f32x4 t = acc[mt][nt];
        t[0] += bvs; t[1] += bvs; t[2] += bvs; t[3] += bvs;
        pv[mt][nt][0] = pk2(t[0], t[1]); pv[mt][nt][1] = pk2(t[2], t[3]);
      }
    }
    #pragma unroll
    for (int dt = 0; dt < 2; ++dt)
      #pragma unroll
      for (int ktj = 0; ktj < 2; ++ktj)
        av[dt][ktj] = build_frag(pv[2 * ktj][dt][0], pv[2 * ktj][dt][1],
                                 pv[2 * ktj + 1][dt][0], pv[2 * ktj + 1][dt][1],
                                 srcA, srcB, ghi);
  }
  __syncthreads();   // all xs x-reads done; attention overwrites xs with 'out'

  // ---- hoist final-GEMM weights NOW: latency hides under whole attention ----
  bf16x8 fw0[8], fw1[8];
  #pragma unroll
  for (int kt = 0; kt < 8; ++kt){
    fw0[kt] = *reinterpret_cast<const bf16x8*>(wo0 + kt * 64);
    fw1[kt] = *reinterpret_cast<const bf16x8*>(wo1 + kt * 64);
  }

  // ---- streamed attention: per i-column-tile nt ----
  const float* bfb = biasF + h * 4096 + (g * 16 + lo) * 4;
  const int oslot0 = ((h * 4 + gq) ^ (lo & 7)) * 16;
  const int oslot1 = ((h * 4 + 2 + gq) ^ (lo & 7)) * 16;
  char* ow = xs_c + lo * 512 + gh;

  #pragma unroll 1
  for (int nt = 0; nt < 4; ++nt){
    const float* bf = bfb + nt * 256;
    const float4 b0 = *reinterpret_cast<const float4*>(bf);
    const float4 b1 = *reinterpret_cast<const float4*>(bf + 1024);
    const float4 b2 = *reinterpret_cast<const float4*>(bf + 2048);
    const float4 b3 = *reinterpret_cast<const float4*>(bf + 3072);
    f32x4 lacc[4];
    #pragma unroll
    for (int jt = 0; jt < 4; ++jt)
      lacc[jt] = mfma16(fk[jt], fq[nt], f32x4{0,0,0,0});
    lacc[0][0] += b0.x; lacc[0][1] += b0.y; lacc[0][2] += b0.z; lacc[0][3] += b0.w;
    lacc[1][0] += b1.x; lacc[1][1] += b1.y; lacc[1][2] += b1.z; lacc[1][3] += b1.w;
    lacc[2][0] += b2.x; lacc[2][1] += b2.y; lacc[2][2] += b2.z; lacc[2][3] += b2.w;
    lacc[3][0] += b3.x; lacc[3][1] += b3.y; lacc[3][2] += b3.z; lacc[3][3] += b3.w;

    // max of 16 via v_max3 tree
    float t0 = max3f(lacc[0][0], lacc[0][1], lacc[0][2]);
    float t1 = max3f(lacc[0][3], lacc[1][0], lacc[1][1]);
    float t2 = max3f(lacc[1][2], lacc[1][3], lacc[2][0]);
    float t3 = max3f(lacc[2][1], lacc[2][2], lacc[2][3]);
    float t4 = max3f(lacc[3][0], lacc[3][1], lacc[3][2]);
    float m  = fmaxf(max3f(t0, t1, t2), max3f(t3, t4, lacc[3][3]));
    m = fmaxf(m, __shfl_xor(m, 16, 64));
    m = fmaxf(m, __shfl_xor(m, 32, 64));

    float ssum = 0.f;
    uint32_t pw[4][2];
    #pragma unroll
    for (int jt = 0; jt < 4; ++jt){
      f32x4 t = lacc[jt];
      #pragma unroll
      for (int r = 0; r < 4; ++r){
        t[r] = exp2f((t[r] - m) * 1.4426950408889634f);
        ssum += t[r];
      }
      pw[jt][0] = pk2(t[0], t[1]);
      pw[jt][1] = pk2(t[2], t[3]);
    }
    ssum += __shfl_xor(ssum, 16, 64);
    ssum += __shfl_xor(ssum, 32, 64);
    const float r0 = 1.f / ssum;

    bf16x8 pf0 = build_frag(pw[0][0], pw[0][1], pw[1][0], pw[1][1], srcA, srcB, ghi);
    bf16x8 pf1 = build_frag(pw[2][0], pw[2][1], pw[3][0], pw[3][1], srcA, srcB, ghi);

    f32x4 o0 = mfma16(av[0][0], pf0, f32x4{0,0,0,0});
    o0 = mfma16(av[0][1], pf1, o0);
    f32x4 o1 = mfma16(av[1][0], pf0, f32x4{0,0,0,0});
    o1 = mfma16(av[1][1], pf1, o1);
    *reinterpret_cast<uint2*>(ow + nt * 8192 + oslot0)
        = make_uint2(pk2(o0[0] * r0, o0[1] * r0), pk2(o0[2] * r0, o0[3] * r0));
    *reinterpret_cast<uint2*>(ow + nt * 8192 + oslot1)
        = make_uint2(pk2(o1[0] * r0, o1[1] * r0), pk2(o1[2] * r0, o1[3] * r0));
  }
  __syncthreads();

  // ---- final GEMM: weights already resident ----
  {
    f32x4 facc[4][2];
    #pragma unroll
    for (int mt = 0; mt < 4; ++mt)
      #pragma unroll
      for (int nt = 0; nt < 2; ++nt) facc[mt][nt] = f32x4{0,0,0,0};

    #pragma unroll 1
    for (int kb = 0; kb < 2; ++kb){
      #pragma unroll
      for (int q = 0; q < 4; ++q){
        const int kt = kb * 4 + q;
        const char* xb = (kt & 1) ? xb1 : xb0;
        const int  im  = (kt >> 1) * 128;
        bf16x8 a[4];
        #pragma unroll
        for (int mt = 0; mt < 4; ++mt)
          a[mt] = *reinterpret_cast<const bf16x8*>(xb + mt * 8192 + im);
        #pragma unroll
        for (int mt = 0; mt < 4; ++mt){
          facc[mt][0] = mfma16(a[mt], fw0[kt], facc[mt][0]);
          facc[mt][1] = mfma16(a[mt], fw1[kt], facc[mt][1]);
        }
      }
    }
    #pragma unroll
    for (int nt = 0; nt < 2; ++nt){
      const int c = h * 32 + nt * 16 + lo;
      const float bd = bod[c];
      float* yb = y + (size_t)b * T * CCH + c;
      #pragma unroll
      for (int mt = 0; mt < 4; ++mt)
        #pragma unroll
        for (int r = 0; r < 4; ++r){
          int i = 16 * mt + 4 * g + r;
          if (i < T) yb[(size_t)i * CCH] = facc[mt][nt][r] + bd;
        }
    }
  }
}

// ---------------- launch ----------------
extern "C" void kernel_launch(void* const* d_in, const int* in_sizes, int n_in,
                              void* d_out, int out_size, void* d_ws, size_t ws_size,
                              hipStream_t stream){
  const float* x    = (const float*)d_in[0];
  const int*   rp   = (const int*)d_in[1];
  const float* btab = (const float*)d_in[2];
  const float* wq   = (const float*)d_in[3];
  const float* bq   = (const float*)d_in[4];
  const float* wk   = (const float*)d_in[5];
  const float* bk   = (const float*)d_in[6];
  const float* wv   = (const float*)d_in[7];
  const float* bv   = (const float*)d_in[8];
  const float* wo   = (const float*)d_in[9];
  const float* bo   = (const float*)d_in[10];
  const float* dw   = (const float*)d_in[11];
  const float* db   = (const float*)d_in[12];
  float* y = (float*)d_out;

  char* ws = (char*)d_ws;
  unsigned short* wqkvT = (unsigned short*)(ws);            // 393216 B
  unsigned short* wodT  = (unsigned short*)(ws + 393216);   // 131072 B
  float* biasF          = (float*)(ws + 524288);            // 131072 B
  float* bqkv           = (float*)(ws + 655360);            // 3072 B
  float* bod            = (float*)(ws + 658432);            // 1024 B

  prep_wqkvT<<<768, 256, 0, stream>>>(wq, wk, wv, wqkvT);
  prep_wodT<<<256, 256, 0, stream>>>(wo, dw, wodT);
  prep_misc<<<9, 256, 0, stream>>>(rp, btab, bq, bk, bv, bo, dw, db, biasF, bqkv, bod);
  wmsa_main<<<1024, 512, 0, stream>>>(x, wqkvT, wodT, biasF, bqkv, bod, y);
}

// Round 15
// 143.045 us; speedup vs baseline: 4.3916x; 4.3916x over previous
//
#include <hip/hip_runtime.h>
#include <stdint.h>

#define T 49
#define CCH 256

typedef __bf16 bf16x8 __attribute__((ext_vector_type(8)));
typedef float f32x4 __attribute__((ext_vector_type(4)));

static __device__ __forceinline__ unsigned short f2bf(float f){
  __bf16 h = (__bf16)f;
  return __builtin_bit_cast(unsigned short, h);
}
static __device__ __forceinline__ uint32_t pk2(float a, float b){
  return (uint32_t)f2bf(a) | ((uint32_t)f2bf(b) << 16);
}
static __device__ __forceinline__ f32x4 mfma16(bf16x8 a, bf16x8 b, f32x4 c){
  return __builtin_amdgcn_mfma_f32_16x16x32_bf16(a, b, c, 0, 0, 0);
}
static __device__ __forceinline__ float max3f(float a, float b, float c){
  return fmaxf(fmaxf(a, b), c);   // fuses to v_max3_f32
}
#define SWZ(row) ((((row) & 7) << 4))

static __device__ __forceinline__ bf16x8 build_frag(uint32_t lo_w0, uint32_t lo_w1,
                                                    uint32_t hi_w0, uint32_t hi_w1,
                                                    int srcA, int srcB, bool use_hi){
  uint32_t a0 = (uint32_t)__shfl((int)lo_w0, srcA, 64);
  uint32_t c0 = (uint32_t)__shfl((int)hi_w0, srcA, 64);
  uint32_t a1 = (uint32_t)__shfl((int)lo_w1, srcA, 64);
  uint32_t c1 = (uint32_t)__shfl((int)hi_w1, srcA, 64);
  uint32_t a2 = (uint32_t)__shfl((int)lo_w0, srcB, 64);
  uint32_t c2 = (uint32_t)__shfl((int)hi_w0, srcB, 64);
  uint32_t a3 = (uint32_t)__shfl((int)lo_w1, srcB, 64);
  uint32_t c3 = (uint32_t)__shfl((int)hi_w1, srcB, 64);
  uint4 u = use_hi ? make_uint4(c0, c1, c2, c3) : make_uint4(a0, a1, a2, a3);
  return __builtin_bit_cast(bf16x8, u);
}

// ---------------- prep kernels (validated) ----------------

__global__ void prep_wqkvT(const float* __restrict__ wq, const float* __restrict__ wk,
                           const float* __restrict__ wv, unsigned short* __restrict__ out){
  int bk = blockIdx.x;            // 0..767
  int p = bk >> 8, kk = bk & 255;
  int n = threadIdx.x;
  const float* w = (p == 0) ? wq : (p == 1 ? wk : wv);
  float scl = (p == 0) ? 0.17677669529663687f : 1.0f;
  out[(size_t)(p * 256 + n) * 256 + kk] = f2bf(w[kk * 256 + n] * scl);
}

__global__ void prep_wodT(const float* __restrict__ wo, const float* __restrict__ dw,
                          unsigned short* __restrict__ out){
  int hd = blockIdx.x;            // 0..255
  int c = threadIdx.x;            // 0..255
  float s = 0.f;
  for (int cp = 0; cp < 256; ++cp) s = fmaf(wo[hd * 256 + cp], dw[cp * 256 + c], s);
  out[(size_t)c * 256 + hd] = f2bf(s);
}

// block 0: bqkv (q-scaled) + bod
// blocks 1..8: biasF (FLOAT) [h][jt][nt][g*16+lo][r] = bias(j=16jt+4g+r, i=16nt+lo)
__global__ void prep_misc(const int* __restrict__ rp, const float* __restrict__ btab,
                          const float* __restrict__ bq, const float* __restrict__ bk,
                          const float* __restrict__ bv, const float* __restrict__ bo,
                          const float* __restrict__ dwm, const float* __restrict__ db,
                          float* __restrict__ biasF, float* __restrict__ bqkv,
                          float* __restrict__ bod){
  int t = threadIdx.x;
  if (blockIdx.x == 0){
    for (int idx = t; idx < 768; idx += 256){
      int p = idx >> 8, n = idx & 255;
      float v = (p == 0) ? bq[n] * 0.17677669529663687f : (p == 1 ? bk[n] : bv[n]);
      bqkv[idx] = v;
    }
    float s = db[t];
    for (int cp = 0; cp < 256; ++cp) s = fmaf(bo[cp], dwm[cp * 256 + t], s);
    bod[t] = s;
  } else {
    int h = blockIdx.x - 1;
    for (int idx = t; idx < 4096; idx += 256){
      int r  = idx & 3;
      int lo = (idx >> 2) & 15;
      int g  = (idx >> 6) & 3;
      int nt = (idx >> 8) & 3;
      int jt = idx >> 10;
      int j = 16 * jt + 4 * g + r;
      int i = 16 * nt + lo;
      float v;
      if (j >= T) v = -1e30f;
      else if (i >= T) v = 0.f;
      else {
        int r0 = rp[i * 49 + j];
        int r1 = rp[2401 + i * 49 + j];
        v = btab[h * 169 + r0 * 13 + r1];
      }
      biasF[h * 4096 + idx] = v;   // idx = jt*1024 + nt*256 + g*64 + lo*4 + r
    }
  }
}

// ---------------- fused main kernel ----------------
// r12 structure at (512,4); ALL weight streams use named-variable 2-deep
// rolling prefetch (no runtime-indexed register arrays -> no scratch, per
// rule #20 diagnosis of r13/r14). biasF f32 + max3 tree.
__launch_bounds__(512, 4)
__global__ void wmsa_main(const float* __restrict__ x,
                          const unsigned short* __restrict__ wqkvT,
                          const unsigned short* __restrict__ wodT,
                          const float* __restrict__ biasF,
                          const float* __restrict__ bqkv,
                          const float* __restrict__ bod,
                          float* __restrict__ y){
  __shared__ unsigned short xs[64 * 256];      // 32 KB, chunk^(row&7) swizzle

  const int b    = blockIdx.x;
  const int tid  = threadIdx.x;
  const int h    = tid >> 6;       // wave == head
  const int lane = tid & 63;
  const int g    = lane >> 4;
  const int lo   = lane & 15;
  char* xs_c = (char*)xs;

  // ---- per-lane constants & base registers ----
  const int  swz  = (lo & 7) << 4;
  const int  gq   = g >> 1;
  const int  gh   = (g & 1) * 8;
  const int  srcA = lo + 16 * ((2 * g) & 3);
  const int  srcB = lo + 16 * ((2 * g + 1) & 3);
  const bool ghi  = (g >= 2);

  const char* xb0 = xs_c + lo * 512 + ((16 * g) ^ swz);
  const char* xb1 = xs_c + lo * 512 + ((64 + 16 * g) ^ swz);

  const char* wk0 = (const char*)wqkvT + (size_t)(256 + h * 32 + lo) * 512 + 16 * g;
  const char* wk1 = wk0 + 16 * 512;
  const char* wq0 = (const char*)wqkvT + (size_t)(h * 32 + lo) * 512 + 16 * g;
  const char* wq1 = wq0 + 16 * 512;
  const char* wv0 = (const char*)wqkvT + (size_t)(512 + h * 32 + lo) * 512 + 16 * g;
  const char* wv1 = wv0 + 16 * 512;
  const char* wo0 = (const char*)wodT + (size_t)(h * 32 + lo) * 512 + 16 * g;
  const char* wo1 = wo0 + 16 * 512;

  // ---- stage x -> xs (batched loads, convert, swizzled writes) ----
  const float* xbp = x + (size_t)b * T * CCH;
  {
    float4 vv[8];
    #pragma unroll
    for (int k2 = 0; k2 < 8; ++k2){
      int idx = tid + k2 * 512;
      int row = idx >> 6, c4 = idx & 63;
      vv[k2] = make_float4(0.f, 0.f, 0.f, 0.f);
      if (row < T) vv[k2] = reinterpret_cast<const float4*>(xbp)[row * 64 + c4];
    }
    #pragma unroll
    for (int k2 = 0; k2 < 8; ++k2){
      int idx = tid + k2 * 512;
      int row = idx >> 6, c4 = idx & 63;
      *reinterpret_cast<uint2*>(xs_c + row * 512 + ((c4 * 8) ^ SWZ(row)))
          = make_uint2(pk2(vv[k2].x, vv[k2].y), pk2(vv[k2].z, vv[k2].w));
    }
  }
  __syncthreads();

  bf16x8 fk[4], fq[4], av[2][2];

  // ---- pass K (transposed GEMM), rolling 2-deep named weight prefetch ----
  {
    f32x4 acc[2][4];
    #pragma unroll
    for (int mt = 0; mt < 2; ++mt)
      #pragma unroll
      for (int nt = 0; nt < 4; ++nt) acc[mt][nt] = f32x4{0,0,0,0};

    bf16x8 cE0 = *reinterpret_cast<const bf16x8*>(wk0);
    bf16x8 cE1 = *reinterpret_cast<const bf16x8*>(wk1);
    bf16x8 cO0 = *reinterpret_cast<const bf16x8*>(wk0 + 64);
    bf16x8 cO1 = *reinterpret_cast<const bf16x8*>(wk1 + 64);

    #pragma unroll 1
    for (int kp = 0; kp < 4; ++kp){
      const int nb = (kp < 3) ? (kp * 128 + 128) : 0;
      bf16x8 nE0 = *reinterpret_cast<const bf16x8*>(wk0 + nb);
      bf16x8 nE1 = *reinterpret_cast<const bf16x8*>(wk1 + nb);
      bf16x8 nO0 = *reinterpret_cast<const bf16x8*>(wk0 + nb + 64);
      bf16x8 nO1 = *reinterpret_cast<const bf16x8*>(wk1 + nb + 64);
      const int im = kp * 128;
      bf16x8 bx[4];
      #pragma unroll
      for (int nt = 0; nt < 4; ++nt)
        bx[nt] = *reinterpret_cast<const bf16x8*>(xb0 + nt * 8192 + im);
      #pragma unroll
      for (int nt = 0; nt < 4; ++nt){
        acc[0][nt] = mfma16(cE0, bx[nt], acc[0][nt]);
        acc[1][nt] = mfma16(cE1, bx[nt], acc[1][nt]);
      }
      #pragma unroll
      for (int nt = 0; nt < 4; ++nt)
        bx[nt] = *reinterpret_cast<const bf16x8*>(xb1 + nt * 8192 + im);
      #pragma unroll
      for (int nt = 0; nt < 4; ++nt){
        acc[0][nt] = mfma16(cO0, bx[nt], acc[0][nt]);
        acc[1][nt] = mfma16(cO1, bx[nt], acc[1][nt]);
      }
      cE0 = nE0; cE1 = nE1; cO0 = nO0; cO1 = nO1;
    }
    uint32_t pkk[2][4][2];
    #pragma unroll
    for (int mt = 0; mt < 2; ++mt){
      const float4 b4 = *reinterpret_cast<const float4*>(bqkv + 256 + h * 32 + 16 * mt + 4 * g);
      #pragma unroll
      for (int nt = 0; nt < 4; ++nt){
        f32x4 t = acc[mt][nt];
        t[0] += b4.x; t[1] += b4.y; t[2] += b4.z; t[3] += b4.w;
        pkk[mt][nt][0] = pk2(t[0], t[1]); pkk[mt][nt][1] = pk2(t[2], t[3]);
      }
    }
    #pragma unroll
    for (int nt = 0; nt < 4; ++nt)
      fk[nt] = build_frag(pkk[0][nt][0], pkk[0][nt][1], pkk[1][nt][0], pkk[1][nt][1], srcA, srcB, ghi);
  }

  // ---- pass Q (transposed GEMM), rolling prefetch ----
  {
    f32x4 acc[2][4];
    #pragma unroll
    for (int mt = 0; mt < 2; ++mt)
      #pragma unroll
      for (int nt = 0; nt < 4; ++nt) acc[mt][nt] = f32x4{0,0,0,0};

    bf16x8 cE0 = *reinterpret_cast<const bf16x8*>(wq0);
    bf16x8 cE1 = *reinterpret_cast<const bf16x8*>(wq1);
    bf16x8 cO0 = *reinterpret_cast<const bf16x8*>(wq0 + 64);
    bf16x8 cO1 = *reinterpret_cast<const bf16x8*>(wq1 + 64);

    #pragma unroll 1
    for (int kp = 0; kp < 4; ++kp){
      const int nb = (kp < 3) ? (kp * 128 + 128) : 0;
      bf16x8 nE0 = *reinterpret_cast<const bf16x8*>(wq0 + nb);
      bf16x8 nE1 = *reinterpret_cast<const bf16x8*>(wq1 + nb);
      bf16x8 nO0 = *reinterpret_cast<const bf16x8*>(wq0 + nb + 64);
      bf16x8 nO1 = *reinterpret_cast<const bf16x8*>(wq1 + nb + 64);
      const int im = kp * 128;
      bf16x8 bx[4];
      #pragma unroll
      for (int nt = 0; nt < 4; ++nt)
        bx[nt] = *reinterpret_cast<const bf16x8*>(xb0 + nt * 8192 + im);
      #pragma unroll
      for (int nt = 0; nt < 4; ++nt){
        acc[0][nt] = mfma16(cE0, bx[nt], acc[0][nt]);
        acc[1][nt] = mfma16(cE1, bx[nt], acc[1][nt]);
      }
      #pragma unroll
      for (int nt = 0; nt < 4; ++nt)
        bx[nt] = *reinterpret_cast<const bf16x8*>(xb1 + nt * 8192 + im);
      #pragma unroll
      for (int nt = 0; nt < 4; ++nt){
        acc[0][nt] = mfma16(cO0, bx[nt], acc[0][nt]);
        acc[1][nt] = mfma16(cO1, bx[nt], acc[1][nt]);
      }
      cE0 = nE0; cE1 = nE1; cO0 = nO0; cO1 = nO1;
    }
    uint32_t pq[2][4][2];
    #pragma unroll
    for (int mt = 0; mt < 2; ++mt){
      const float4 b4 = *reinterpret_cast<const float4*>(bqkv + h * 32 + 16 * mt + 4 * g);
      #pragma unroll
      for (int nt = 0; nt < 4; ++nt){
        f32x4 t = acc[mt][nt];
        t[0] += b4.x; t[1] += b4.y; t[2] += b4.z; t[3] += b4.w;
        pq[mt][nt][0] = pk2(t[0], t[1]); pq[mt][nt][1] = pk2(t[2], t[3]);
      }
    }
    #pragma unroll
    for (int nt = 0; nt < 4; ++nt)
      fq[nt] = build_frag(pq[0][nt][0], pq[0][nt][1], pq[1][nt][0], pq[1][nt][1], srcA, srcB, ghi);
  }

  // ---- pass V (normal GEMM), rolling prefetch; av in-register ----
  {
    f32x4 acc[4][2];
    #pragma unroll
    for (int mt = 0; mt < 4; ++mt)
      #pragma unroll
      for (int nt = 0; nt < 2; ++nt) acc[mt][nt] = f32x4{0,0,0,0};

    bf16x8 cE0 = *reinterpret_cast<const bf16x8*>(wv0);
    bf16x8 cE1 = *reinterpret_cast<const bf16x8*>(wv1);
    bf16x8 cO0 = *reinterpret_cast<const bf16x8*>(wv0 + 64);
    bf16x8 cO1 = *reinterpret_cast<const bf16x8*>(wv1 + 64);

    #pragma unroll 1
    for (int kp = 0; kp < 4; ++kp){
      const int nb = (kp < 3) ? (kp * 128 + 128) : 0;
      bf16x8 nE0 = *reinterpret_cast<const bf16x8*>(wv0 + nb);
      bf16x8 nE1 = *reinterpret_cast<const bf16x8*>(wv1 + nb);
      bf16x8 nO0 = *reinterpret_cast<const bf16x8*>(wv0 + nb + 64);
      bf16x8 nO1 = *reinterpret_cast<const bf16x8*>(wv1 + nb + 64);
      const int im = kp * 128;
      bf16x8 ax[4];
      #pragma unroll
      for (int mt = 0; mt < 4; ++mt)
        ax[mt] = *reinterpret_cast<const bf16x8*>(xb0 + mt * 8192 + im);
      #pragma unroll
      for (int mt = 0; mt < 4; ++mt){
        acc[mt][0] = mfma16(ax[mt], cE0, acc[mt][0]);
        acc[mt][1] = mfma16(ax[mt], cE1, acc[mt][1]);
      }
      #pragma unroll
      for (int mt = 0; mt < 4; ++mt)
        ax[mt] = *reinterpret_cast<const bf16x8*>(xb1 + mt * 8192 + im);
      #pragma unroll
      for (int mt = 0; mt < 4; ++mt){
        acc[mt][0] = mfma16(ax[mt], cO0, acc[mt][0]);
        acc[mt][1] = mfma16(ax[mt], cO1, acc[mt][1]);
      }
      cE0 = nE0; cE1 = nE1; cO0 = nO0; cO1 = nO1;
    }
    uint32_t pv[4][2][2];
    #pragma unroll
    for (int nt = 0; nt < 2; ++nt){
      const float bvs = bqkv[512 + h * 32 + 16 * nt + lo];
      #pragma unroll
      for (int mt = 0; mt < 4; ++mt){
        f32x4 t = acc[mt][nt];
        t[0] += bvs; t[1] += bvs; t[2] += bvs; t[3] += bvs;
        pv[mt][nt][0] = pk2(t[0], t[1]); pv[mt][nt][1] = pk2(t[2], t[3]);
      }
    }
    #pragma unroll
    for (int dt = 0; dt < 2; ++dt)
      #pragma unroll
      for (int ktj = 0; ktj < 2; ++ktj)
        av[dt][ktj] = build_frag(pv[2 * ktj][dt][0], pv[2 * ktj][dt][1],
                                 pv[2 * ktj + 1][dt][0], pv[2 * ktj + 1][dt][1],
                                 srcA, srcB, ghi);
  }
  __syncthreads();   // all xs x-reads done; attention overwrites xs with 'out'

  // ---- streamed attention: per i-column-tile nt ----
  const float* bfb = biasF + h * 4096 + (g * 16 + lo) * 4;
  const int oslot0 = ((h * 4 + gq) ^ (lo & 7)) * 16;
  const int oslot1 = ((h * 4 + 2 + gq) ^ (lo & 7)) * 16;
  char* ow = xs_c + lo * 512 + gh;

  #pragma unroll 1
  for (int nt = 0; nt < 4; ++nt){
    const float* bf = bfb + nt * 256;
    const float4 b0 = *reinterpret_cast<const float4*>(bf);
    const float4 b1 = *reinterpret_cast<const float4*>(bf + 1024);
    const float4 b2 = *reinterpret_cast<const float4*>(bf + 2048);
    const float4 b3 = *reinterpret_cast<const float4*>(bf + 3072);
    f32x4 lacc[4];
    #pragma unroll
    for (int jt = 0; jt < 4; ++jt)
      lacc[jt] = mfma16(fk[jt], fq[nt], f32x4{0,0,0,0});
    lacc[0][0] += b0.x; lacc[0][1] += b0.y; lacc[0][2] += b0.z; lacc[0][3] += b0.w;
    lacc[1][0] += b1.x; lacc[1][1] += b1.y; lacc[1][2] += b1.z; lacc[1][3] += b1.w;
    lacc[2][0] += b2.x; lacc[2][1] += b2.y; lacc[2][2] += b2.z; lacc[2][3] += b2.w;
    lacc[3][0] += b3.x; lacc[3][1] += b3.y; lacc[3][2] += b3.z; lacc[3][3] += b3.w;

    // max of 16 via v_max3 tree
    float t0 = max3f(lacc[0][0], lacc[0][1], lacc[0][2]);
    float t1 = max3f(lacc[0][3], lacc[1][0], lacc[1][1]);
    float t2 = max3f(lacc[1][2], lacc[1][3], lacc[2][0]);
    float t3 = max3f(lacc[2][1], lacc[2][2], lacc[2][3]);
    float t4 = max3f(lacc[3][0], lacc[3][1], lacc[3][2]);
    float m  = fmaxf(max3f(t0, t1, t2), max3f(t3, t4, lacc[3][3]));
    m = fmaxf(m, __shfl_xor(m, 16, 64));
    m = fmaxf(m, __shfl_xor(m, 32, 64));

    float ssum = 0.f;
    uint32_t pw[4][2];
    #pragma unroll
    for (int jt = 0; jt < 4; ++jt){
      f32x4 t = lacc[jt];
      #pragma unroll
      for (int r = 0; r < 4; ++r){
        t[r] = exp2f((t[r] - m) * 1.4426950408889634f);
        ssum += t[r];
      }
      pw[jt][0] = pk2(t[0], t[1]);
      pw[jt][1] = pk2(t[2], t[3]);
    }
    ssum += __shfl_xor(ssum, 16, 64);
    ssum += __shfl_xor(ssum, 32, 64);
    const float r0 = 1.f / ssum;

    bf16x8 pf0 = build_frag(pw[0][0], pw[0][1], pw[1][0], pw[1][1], srcA, srcB, ghi);
    bf16x8 pf1 = build_frag(pw[2][0], pw[2][1], pw[3][0], pw[3][1], srcA, srcB, ghi);

    f32x4 o0 = mfma16(av[0][0], pf0, f32x4{0,0,0,0});
    o0 = mfma16(av[0][1], pf1, o0);
    f32x4 o1 = mfma16(av[1][0], pf0, f32x4{0,0,0,0});
    o1 = mfma16(av[1][1], pf1, o1);
    *reinterpret_cast<uint2*>(ow + nt * 8192 + oslot0)
        = make_uint2(pk2(o0[0] * r0, o0[1] * r0), pk2(o0[2] * r0, o0[3] * r0));
    *reinterpret_cast<uint2*>(ow + nt * 8192 + oslot1)
        = make_uint2(pk2(o1[0] * r0, o1[1] * r0), pk2(o1[2] * r0, o1[3] * r0));
  }
  __syncthreads();

  // ---- final GEMM, rolling prefetch ----
  {
    f32x4 facc[4][2];
    #pragma unroll
    for (int mt = 0; mt < 4; ++mt)
      #pragma unroll
      for (int nt = 0; nt < 2; ++nt) facc[mt][nt] = f32x4{0,0,0,0};

    bf16x8 cE0 = *reinterpret_cast<const bf16x8*>(wo0);
    bf16x8 cE1 = *reinterpret_cast<const bf16x8*>(wo1);
    bf16x8 cO0 = *reinterpret_cast<const bf16x8*>(wo0 + 64);
    bf16x8 cO1 = *reinterpret_cast<const bf16x8*>(wo1 + 64);

    #pragma unroll 1
    for (int kp = 0; kp < 4; ++kp){
      const int nb = (kp < 3) ? (kp * 128 + 128) : 0;
      bf16x8 nE0 = *reinterpret_cast<const bf16x8*>(wo0 + nb);
      bf16x8 nE1 = *reinterpret_cast<const bf16x8*>(wo1 + nb);
      bf16x8 nO0 = *reinterpret_cast<const bf16x8*>(wo0 + nb + 64);
      bf16x8 nO1 = *reinterpret_cast<const bf16x8*>(wo1 + nb + 64);
      const int im = kp * 128;
      bf16x8 a[4];
      #pragma unroll
      for (int mt = 0; mt < 4; ++mt)
        a[mt] = *reinterpret_cast<const bf16x8*>(xb0 + mt * 8192 + im);
      #pragma unroll
      for (int mt = 0; mt < 4; ++mt){
        facc[mt][0] = mfma16(a[mt], cE0, facc[mt][0]);
        facc[mt][1] = mfma16(a[mt], cE1, facc[mt][1]);
      }
      #pragma unroll
      for (int mt = 0; mt < 4; ++mt)
        a[mt] = *reinterpret_cast<const bf16x8*>(xb1 + mt * 8192 + im);
      #pragma unroll
      for (int mt = 0; mt < 4; ++mt){
        facc[mt][0] = mfma16(a[mt], cO0, facc[mt][0]);
        facc[mt][1] = mfma16(a[mt], cO1, facc[mt][1]);
      }
      cE0 = nE0; cE1 = nE1; cO0 = nO0; cO1 = nO1;
    }
    #pragma unroll
    for (int nt = 0; nt < 2; ++nt){
      const int c = h * 32 + nt * 16 + lo;
      const float bd = bod[c];
      float* yb = y + (size_t)b * T * CCH + c;
      #pragma unroll
      for (int mt = 0; mt < 4; ++mt)
        #pragma unroll
        for (int r = 0; r < 4; ++r){
          int i = 16 * mt + 4 * g + r;
          if (i < T) yb[(size_t)i * CCH] = facc[mt][nt][r] + bd;
        }
    }
  }
}

// ---------------- launch ----------------
extern "C" void kernel_launch(void* const* d_in, const int* in_sizes, int n_in,
                              void* d_out, int out_size, void* d_ws, size_t ws_size,
                              hipStream_t stream){
  const float* x    = (const float*)d_in[0];
  const int*   rp   = (const int*)d_in[1];
  const float* btab = (const float*)d_in[2];
  const float* wq   = (const float*)d_in[3];
  const float* bq   = (const float*)d_in[4];
  const float* wk   = (const float*)d_in[5];
  const float* bk   = (const float*)d_in[6];
  const float* wv   = (const float*)d_in[7];
  const float* bv   = (const float*)d_in[8];
  const float* wo   = (const float*)d_in[9];
  const float* bo   = (const float*)d_in[10];
  const float* dw   = (const float*)d_in[11];
  const float* db   = (const float*)d_in[12];
  float* y = (float*)d_out;

  char* ws = (char*)d_ws;
  unsigned short* wqkvT = (unsigned short*)(ws);            // 393216 B
  unsigned short* wodT  = (unsigned short*)(ws + 393216);   // 131072 B
  float* biasF          = (float*)(ws + 524288);            // 131072 B
  float* bqkv           = (float*)(ws + 655360);            // 3072 B
  float* bod            = (float*)(ws + 658432);            // 1024 B

  prep_wqkvT<<<768, 256, 0, stream>>>(wq, wk, wv, wqkvT);
  prep_wodT<<<256, 256, 0, stream>>>(wo, dw, wodT);
  prep_misc<<<9, 256, 0, stream>>>(rp, btab, bq, bk, bv, bo, dw, db, biasF, bqkv, bod);
  wmsa_main<<<1024, 512, 0, stream>>>(x, wqkvT, wodT, biasF, bqkv, bod, y);
}